// Round 1
// baseline (235.654 us; speedup 1.0000x reference)
//
#include <hip/hip_runtime.h>

#define HIDDEN 256
#define GAMMA_F 12.0f
#define BATCH 8

// One wave (64 lanes) per chunk of 64 consecutive outputs n.
// Per output: lanes cooperatively read the 256-float tail row (float4/lane,
// 1KB coalesced), compute sum |hr - t|, butterfly-reduce, lane i latches the
// result; one coalesced 64-float store per chunk.
__global__ __launch_bounds__(256) void kge_transe_kernel(
    const float* __restrict__ ent,
    const float* __restrict__ rel,
    const int*  __restrict__ pos,
    const int*  __restrict__ neg,
    float* __restrict__ out,
    int nneg, int nchunks)
{
    const int b     = blockIdx.y;
    const int lane  = threadIdx.x & 63;
    const int wave  = threadIdx.x >> 6;
    const int chunk = blockIdx.x * 4 + wave;
    if (chunk >= nchunks) return;
    const int n0 = chunk * 64;

    // head + relation for this batch row: 4 floats per lane, lives in regs
    const int hidx = pos[b * 3 + 0];
    const int ridx = pos[b * 3 + 1];
    const float4 h4 = *(const float4*)(ent + (size_t)hidx * HIDDEN + lane * 4);
    const float4 r4 = *(const float4*)(rel + (size_t)ridx * HIDDEN + lane * 4);
    const float4 hr = make_float4(h4.x + r4.x, h4.y + r4.y,
                                  h4.z + r4.z, h4.w + r4.w);

    // coalesced load of this chunk's 64 gather indices
    const int n_lane = n0 + lane;
    const int myidx = (n_lane < nneg) ? neg[(size_t)b * nneg + n_lane] : 0;

    const int valid = (nneg - n0 < 64) ? (nneg - n0) : 64;
    float res = 0.0f;

    #pragma unroll 4
    for (int i = 0; i < 64; ++i) {
        if (i >= valid) break;
        const int t = __shfl(myidx, i, 64);
        const float4 t4 = *(const float4*)(ent + (size_t)t * HIDDEN + lane * 4);
        float s = fabsf(hr.x - t4.x) + fabsf(hr.y - t4.y)
                + fabsf(hr.z - t4.z) + fabsf(hr.w - t4.w);
        // butterfly reduce over 64 lanes -> all lanes hold the row sum
        #pragma unroll
        for (int off = 1; off < 64; off <<= 1)
            s += __shfl_xor(s, off, 64);
        if (lane == i) res = GAMMA_F - s;
    }

    if (n_lane < nneg) out[(size_t)b * nneg + n_lane] = res;  // coalesced store
}

extern "C" void kernel_launch(void* const* d_in, const int* in_sizes, int n_in,
                              void* d_out, int out_size, void* d_ws, size_t ws_size,
                              hipStream_t stream) {
    const float* ent = (const float*)d_in[0];   // [100000, 256] f32
    const float* rel = (const float*)d_in[1];   // [500, 256]    f32
    const int*   pos = (const int*)d_in[2];     // [8, 3]        int
    const int*   neg = (const int*)d_in[3];     // [8, 100000]   int
    float* out = (float*)d_out;                 // [8, 100000]   f32

    const int nneg   = in_sizes[3] / BATCH;       // 100000
    const int nchunks = (nneg + 63) / 64;         // 1563
    dim3 grid((nchunks + 3) / 4, BATCH);          // 4 waves/block, 1 chunk/wave
    kge_transe_kernel<<<grid, 256, 0, stream>>>(ent, rel, pos, neg, out,
                                                nneg, nchunks);
}

// Round 2
// 197.667 us; speedup vs baseline: 1.1922x; 1.1922x over previous
//
#include <hip/hip_runtime.h>

#define HIDDEN 256
#define GAMMA_F 12.0f
#define BATCH 8

// ---------------------------------------------------------------------------
// Kernel A: stream the entity table once; for each entity row e compute
// dist[e][b] = GAMMA - || (head_b + rel_b) - ent_e ||_1   for all 8 batches.
// One wave per entity row: lane covers dims [lane*4, lane*4+4) as float4.
// Reduction: merge-tree — offsets 1,2,4 pair-merge the 8 batch partials
// (after which lane l%8 holds batch l%8 summed over its 8-lane group), then
// offsets 8,16,32 butterfly. 10 shuffles/row total instead of 48.
// ---------------------------------------------------------------------------
__global__ __launch_bounds__(256) void kge_dist_kernel(
    const float* __restrict__ ent,
    const float* __restrict__ rel,
    const int*  __restrict__ pos,
    float* __restrict__ dist,   // [nent, 8]
    int nent)
{
    const int lane = threadIdx.x & 63;
    const int wave = threadIdx.x >> 6;
    const int e = blockIdx.x * 4 + wave;
    if (e >= nent) return;

    // hr[b] = head_b + rel_b (same 16 KB for every wave -> L1-resident)
    float4 hr[BATCH];
    #pragma unroll
    for (int b = 0; b < BATCH; ++b) {
        const int hidx = pos[b * 3 + 0];
        const int ridx = pos[b * 3 + 1];
        const float4 h4 = *(const float4*)(ent + (size_t)hidx * HIDDEN + lane * 4);
        const float4 r4 = *(const float4*)(rel + (size_t)ridx * HIDDEN + lane * 4);
        hr[b] = make_float4(h4.x + r4.x, h4.y + r4.y, h4.z + r4.z, h4.w + r4.w);
    }

    // the streamed row: fully coalesced 1KB per wave
    const float4 t4 = *(const float4*)(ent + (size_t)e * HIDDEN + lane * 4);

    float acc[BATCH];
    #pragma unroll
    for (int b = 0; b < BATCH; ++b) {
        acc[b] = fabsf(hr[b].x - t4.x) + fabsf(hr[b].y - t4.y)
               + fabsf(hr[b].z - t4.z) + fabsf(hr[b].w - t4.w);
    }

    // merge-reduce 8 values across 64 lanes (batch bit k = lane bit k)
    float v[4];
    {
        const bool p = lane & 1;
        #pragma unroll
        for (int k = 0; k < 4; ++k) {
            const float keep = p ? acc[2 * k + 1] : acc[2 * k];
            const float give = p ? acc[2 * k]     : acc[2 * k + 1];
            v[k] = keep + __shfl_xor(give, 1, 64);
        }
    }
    float w2[2];
    {
        const bool p = (lane >> 1) & 1;
        #pragma unroll
        for (int k = 0; k < 2; ++k) {
            const float keep = p ? v[2 * k + 1] : v[2 * k];
            const float give = p ? v[2 * k]     : v[2 * k + 1];
            w2[k] = keep + __shfl_xor(give, 2, 64);
        }
    }
    float s;
    {
        const bool p = (lane >> 2) & 1;
        const float keep = p ? w2[1] : w2[0];
        const float give = p ? w2[0] : w2[1];
        s = keep + __shfl_xor(give, 4, 64);
    }
    s += __shfl_xor(s, 8, 64);
    s += __shfl_xor(s, 16, 64);
    s += __shfl_xor(s, 32, 64);

    if (lane < BATCH)
        dist[(size_t)e * BATCH + lane] = GAMMA_F - s;
}

// ---------------------------------------------------------------------------
// Kernel B: out[b,n] = dist[neg[b,n]*8 + b]. dist is 3.2 MB -> L2-resident.
// ---------------------------------------------------------------------------
__global__ __launch_bounds__(256) void kge_gather_kernel(
    const int*  __restrict__ neg,
    const float* __restrict__ dist,
    float* __restrict__ out,
    int nneg)
{
    const int b = blockIdx.y;
    const int n = blockIdx.x * 256 + threadIdx.x;
    if (n >= nneg) return;
    const size_t off = (size_t)b * nneg + n;
    out[off] = dist[(size_t)neg[off] * BATCH + b];
}

// ---------------------------------------------------------------------------
// Fallback (round-1 kernel) in case ws_size is too small for the dist table.
// ---------------------------------------------------------------------------
__global__ __launch_bounds__(256) void kge_transe_kernel(
    const float* __restrict__ ent,
    const float* __restrict__ rel,
    const int*  __restrict__ pos,
    const int*  __restrict__ neg,
    float* __restrict__ out,
    int nneg, int nchunks)
{
    const int b     = blockIdx.y;
    const int lane  = threadIdx.x & 63;
    const int wave  = threadIdx.x >> 6;
    const int chunk = blockIdx.x * 4 + wave;
    if (chunk >= nchunks) return;
    const int n0 = chunk * 64;

    const int hidx = pos[b * 3 + 0];
    const int ridx = pos[b * 3 + 1];
    const float4 h4 = *(const float4*)(ent + (size_t)hidx * HIDDEN + lane * 4);
    const float4 r4 = *(const float4*)(rel + (size_t)ridx * HIDDEN + lane * 4);
    const float4 hr = make_float4(h4.x + r4.x, h4.y + r4.y,
                                  h4.z + r4.z, h4.w + r4.w);

    const int n_lane = n0 + lane;
    const int myidx = (n_lane < nneg) ? neg[(size_t)b * nneg + n_lane] : 0;
    const int valid = (nneg - n0 < 64) ? (nneg - n0) : 64;
    float res = 0.0f;

    #pragma unroll 4
    for (int i = 0; i < 64; ++i) {
        if (i >= valid) break;
        const int t = __shfl(myidx, i, 64);
        const float4 t4 = *(const float4*)(ent + (size_t)t * HIDDEN + lane * 4);
        float s = fabsf(hr.x - t4.x) + fabsf(hr.y - t4.y)
                + fabsf(hr.z - t4.z) + fabsf(hr.w - t4.w);
        #pragma unroll
        for (int off = 1; off < 64; off <<= 1)
            s += __shfl_xor(s, off, 64);
        if (lane == i) res = GAMMA_F - s;
    }

    if (n_lane < nneg) out[(size_t)b * nneg + n_lane] = res;
}

extern "C" void kernel_launch(void* const* d_in, const int* in_sizes, int n_in,
                              void* d_out, int out_size, void* d_ws, size_t ws_size,
                              hipStream_t stream) {
    const float* ent = (const float*)d_in[0];   // [100000, 256] f32
    const float* rel = (const float*)d_in[1];   // [500, 256]    f32
    const int*   pos = (const int*)d_in[2];     // [8, 3]        int32
    const int*   neg = (const int*)d_in[3];     // [8, 100000]   int32
    float* out = (float*)d_out;                 // [8, 100000]   f32

    const int nent = in_sizes[0] / HIDDEN;      // 100000
    const int nneg = in_sizes[3] / BATCH;       // 100000
    const size_t dist_bytes = (size_t)nent * BATCH * sizeof(float);  // 3.2 MB

    if (ws_size >= dist_bytes) {
        float* dist = (float*)d_ws;
        // A: stream entity table once, all-batch distances
        dim3 gridA((nent + 3) / 4);
        kge_dist_kernel<<<gridA, 256, 0, stream>>>(ent, rel, pos, dist, nent);
        // B: 4B gather from L2-resident dist table
        dim3 gridB((nneg + 255) / 256, BATCH);
        kge_gather_kernel<<<gridB, 256, 0, stream>>>(neg, dist, out, nneg);
    } else {
        const int nchunks = (nneg + 63) / 64;
        dim3 grid((nchunks + 3) / 4, BATCH);
        kge_transe_kernel<<<grid, 256, 0, stream>>>(ent, rel, pos, neg, out,
                                                    nneg, nchunks);
    }
}

// Round 3
// 179.979 us; speedup vs baseline: 1.3093x; 1.0983x over previous
//
#include <hip/hip_runtime.h>

#define HIDDEN 256
#define GAMMA_F 12.0f
#define BATCH 8

// ---------------------------------------------------------------------------
// Kernel A: stream the entity table once with persistent waves.
// Lane decomposition: b = lane>>3 (batch), g = lane&7 (dim group).
// Lane accumulates sum_{k=0..7} |hr[b][(g+8k)*4..+4) - ent[e][...]| (32 dims),
// then 3 shfl_xor (1,2,4) reduce over g. hr lives in 32 VGPRs, loaded once.
// Each k-load covers bytes [k*128,(k+1)*128) of the row, replicated across
// the 8 b-groups -> fully coalesced, 1KB/row/wave.
// ---------------------------------------------------------------------------
__global__ __launch_bounds__(256) void kge_dist_kernel(
    const float* __restrict__ ent,
    const float* __restrict__ rel,
    const int*  __restrict__ pos,
    float* __restrict__ dist,   // [nent, 8]
    int nent)
{
    const int lane = threadIdx.x & 63;
    const int b = lane >> 3;
    const int g = lane & 7;
    const int wave_gid = (blockIdx.x * 256 + threadIdx.x) >> 6;
    const int nwaves = gridDim.x * 4;

    // hr[k] = (head_b + rel_b) at dims [(g+8k)*4, +4) — 32 VGPRs, once per wave
    const int hidx = pos[b * 3 + 0];
    const int ridx = pos[b * 3 + 1];
    float4 hr[8];
    #pragma unroll
    for (int k = 0; k < 8; ++k) {
        const int doff = (g + 8 * k) * 4;
        const float4 h4 = *(const float4*)(ent + (size_t)hidx * HIDDEN + doff);
        const float4 r4 = *(const float4*)(rel + (size_t)ridx * HIDDEN + doff);
        hr[k] = make_float4(h4.x + r4.x, h4.y + r4.y, h4.z + r4.z, h4.w + r4.w);
    }

    for (int e = wave_gid; e < nent; e += nwaves) {
        const float* row = ent + (size_t)e * HIDDEN;
        float s = 0.0f;
        #pragma unroll
        for (int k = 0; k < 8; ++k) {
            const float4 t4 = *(const float4*)(row + (g + 8 * k) * 4);
            s += fabsf(hr[k].x - t4.x) + fabsf(hr[k].y - t4.y)
               + fabsf(hr[k].z - t4.z) + fabsf(hr[k].w - t4.w);
        }
        // reduce over g (lane bits 0..2); b (bits 3..5) untouched
        s += __shfl_xor(s, 1, 64);
        s += __shfl_xor(s, 2, 64);
        s += __shfl_xor(s, 4, 64);
        if (g == 0)
            dist[(size_t)e * BATCH + b] = GAMMA_F - s;  // 8 lanes, 32B contig
    }
}

// ---------------------------------------------------------------------------
// Kernel B: out[b,n] = dist[neg[b,n]*8 + b]. dist (3.2MB) fits per-XCD L2.
// 4 outputs/thread: int4 index load, 4 scalar gathers, float4 store.
// ---------------------------------------------------------------------------
__global__ __launch_bounds__(256) void kge_gather_kernel(
    const int*  __restrict__ neg,
    const float* __restrict__ dist,
    float* __restrict__ out,
    int nneg)
{
    const int b = blockIdx.y;
    const int n = (blockIdx.x * 256 + threadIdx.x) * 4;
    if (n + 3 < nneg) {
        const int4 idx = *(const int4*)(neg + (size_t)b * nneg + n);
        float4 r;
        r.x = dist[(size_t)idx.x * BATCH + b];
        r.y = dist[(size_t)idx.y * BATCH + b];
        r.z = dist[(size_t)idx.z * BATCH + b];
        r.w = dist[(size_t)idx.w * BATCH + b];
        *(float4*)(out + (size_t)b * nneg + n) = r;
    } else {
        for (int i = n; i < nneg; ++i)
            out[(size_t)b * nneg + i] =
                dist[(size_t)neg[(size_t)b * nneg + i] * BATCH + b];
    }
}

extern "C" void kernel_launch(void* const* d_in, const int* in_sizes, int n_in,
                              void* d_out, int out_size, void* d_ws, size_t ws_size,
                              hipStream_t stream) {
    const float* ent = (const float*)d_in[0];   // [100000, 256] f32
    const float* rel = (const float*)d_in[1];   // [500, 256]    f32
    const int*   pos = (const int*)d_in[2];     // [8, 3]        int32
    const int*   neg = (const int*)d_in[3];     // [8, 100000]   int32
    float* out = (float*)d_out;                 // [8, 100000]   f32

    const int nent = in_sizes[0] / HIDDEN;      // 100000
    const int nneg = in_sizes[3] / BATCH;       // 100000
    float* dist = (float*)d_ws;                 // 3.2 MB (ws is larger)

    // A: persistent waves stream the entity table once
    kge_dist_kernel<<<1024, 256, 0, stream>>>(ent, rel, pos, dist, nent);

    // B: L2-resident 4B gather, 4 outputs/thread
    const int ngroups = (nneg + 3) / 4;
    dim3 gridB((ngroups + 255) / 256, BATCH);
    kge_gather_kernel<<<gridB, 256, 0, stream>>>(neg, dist, out, nneg);
}

// Round 4
// 179.809 us; speedup vs baseline: 1.3106x; 1.0009x over previous
//
#include <hip/hip_runtime.h>

#define HIDDEN 256
#define GAMMA_F 12.0f
#define BATCH 8

// ---------------------------------------------------------------------------
// Kernel A: stream the entity table once with persistent waves, 2 rows per
// iteration (16 loads in flight -> guaranteed MLP; compiler overlaps row e
// compute with row e+1 load drain via partial vmcnt waits).
// Lane decomposition: b = lane>>3 (batch), g = lane&7 (dim group of 32 dims).
// Reduction: pair-merge over g-bit 0 folds BOTH rows in one shuffle (even-g
// lanes carry row e, odd-g lanes row e+1), then butterfly over g-bits 1,2.
// 3 shuffles total for 2 rows. Store: 16 lanes write 64B contiguous.
// ---------------------------------------------------------------------------
__global__ __launch_bounds__(256) void kge_dist_kernel(
    const float* __restrict__ ent,
    const float* __restrict__ rel,
    const int*  __restrict__ pos,
    float* __restrict__ dist,   // [nent, 8]
    int nent)
{
    const int lane = threadIdx.x & 63;
    const int b = lane >> 3;
    const int g = lane & 7;
    const int wave_gid = (blockIdx.x * 256 + threadIdx.x) >> 6;
    const int nwaves = gridDim.x * 4;

    // hr[k] = (head_b + rel_b) at dims [(g+8k)*4, +4) — 32 VGPRs, once per wave
    const int hidx = pos[b * 3 + 0];
    const int ridx = pos[b * 3 + 1];
    float4 hr[8];
    #pragma unroll
    for (int k = 0; k < 8; ++k) {
        const int doff = (g + 8 * k) * 4;
        const float4 h4 = *(const float4*)(ent + (size_t)hidx * HIDDEN + doff);
        const float4 r4 = *(const float4*)(rel + (size_t)ridx * HIDDEN + doff);
        hr[k] = make_float4(h4.x + r4.x, h4.y + r4.y, h4.z + r4.z, h4.w + r4.w);
    }

    const int stride = nwaves * 2;
    for (int e = wave_gid * 2; e + 1 < nent; e += stride) {
        const float* row0 = ent + (size_t)e * HIDDEN;
        const float* row1 = row0 + HIDDEN;

        // issue all 16 loads (2 KB) before any use
        float4 t0[8], t1[8];
        #pragma unroll
        for (int k = 0; k < 8; ++k) t0[k] = *(const float4*)(row0 + (g + 8 * k) * 4);
        #pragma unroll
        for (int k = 0; k < 8; ++k) t1[k] = *(const float4*)(row1 + (g + 8 * k) * 4);

        float s0 = 0.0f, s1 = 0.0f;
        #pragma unroll
        for (int k = 0; k < 8; ++k) {
            s0 += fabsf(hr[k].x - t0[k].x) + fabsf(hr[k].y - t0[k].y)
                + fabsf(hr[k].z - t0[k].z) + fabsf(hr[k].w - t0[k].w);
        }
        #pragma unroll
        for (int k = 0; k < 8; ++k) {
            s1 += fabsf(hr[k].x - t1[k].x) + fabsf(hr[k].y - t1[k].y)
                + fabsf(hr[k].z - t1[k].z) + fabsf(hr[k].w - t1[k].w);
        }

        // pair-merge over g-bit 0: even-g lanes accumulate row0, odd-g row1
        const bool p = g & 1;
        float m = (p ? s1 : s0) + __shfl_xor(p ? s0 : s1, 1, 64);
        // butterfly over g-bits 1,2 (same row within each parity class)
        m += __shfl_xor(m, 2, 64);
        m += __shfl_xor(m, 4, 64);

        // g==0 lanes hold row e sums, g==1 lanes row e+1: 64B contiguous store
        if (g < 2)
            dist[(size_t)(e + g) * BATCH + b] = GAMMA_F - m;
    }

    // tail for odd nent (not hit at nent=100000)
    if ((nent & 1) && wave_gid == 0) {
        const int e = nent - 1;
        const float* row = ent + (size_t)e * HIDDEN;
        float s = 0.0f;
        #pragma unroll
        for (int k = 0; k < 8; ++k) {
            const float4 t4 = *(const float4*)(row + (g + 8 * k) * 4);
            s += fabsf(hr[k].x - t4.x) + fabsf(hr[k].y - t4.y)
               + fabsf(hr[k].z - t4.z) + fabsf(hr[k].w - t4.w);
        }
        s += __shfl_xor(s, 1, 64);
        s += __shfl_xor(s, 2, 64);
        s += __shfl_xor(s, 4, 64);
        if (g == 0) dist[(size_t)e * BATCH + b] = GAMMA_F - s;
    }
}

// ---------------------------------------------------------------------------
// Kernel B: out[b,n] = dist[neg[b,n]*8 + b]. dist (3.2MB) is L2/L3-resident.
// 2 outputs/thread: int2 index load, 2 independent gathers, float2 store.
// 400k threads -> ~6 waves/SIMD of TLP to cover gather latency.
// ---------------------------------------------------------------------------
__global__ __launch_bounds__(256) void kge_gather_kernel(
    const int*  __restrict__ neg,
    const float* __restrict__ dist,
    float* __restrict__ out,
    int nneg)
{
    const int b = blockIdx.y;
    const int n = (blockIdx.x * 256 + threadIdx.x) * 2;
    if (n + 1 < nneg) {
        const int2 idx = *(const int2*)(neg + (size_t)b * nneg + n);
        float2 r;
        r.x = dist[(size_t)idx.x * BATCH + b];
        r.y = dist[(size_t)idx.y * BATCH + b];
        *(float2*)(out + (size_t)b * nneg + n) = r;
    } else if (n < nneg) {
        out[(size_t)b * nneg + n] =
            dist[(size_t)neg[(size_t)b * nneg + n] * BATCH + b];
    }
}

extern "C" void kernel_launch(void* const* d_in, const int* in_sizes, int n_in,
                              void* d_out, int out_size, void* d_ws, size_t ws_size,
                              hipStream_t stream) {
    const float* ent = (const float*)d_in[0];   // [100000, 256] f32
    const float* rel = (const float*)d_in[1];   // [500, 256]    f32
    const int*   pos = (const int*)d_in[2];     // [8, 3]        int32
    const int*   neg = (const int*)d_in[3];     // [8, 100000]   int32
    float* out = (float*)d_out;                 // [8, 100000]   f32

    const int nent = in_sizes[0] / HIDDEN;      // 100000
    const int nneg = in_sizes[3] / BATCH;       // 100000
    float* dist = (float*)d_ws;                 // 3.2 MB (ws is larger)

    // A: persistent waves, 2 rows/iter, 2048 blocks (8/CU for full residency)
    kge_dist_kernel<<<2048, 256, 0, stream>>>(ent, rel, pos, dist, nent);

    // B: L2-resident 4B gather, 2 outputs/thread
    const int ngroups = (nneg + 1) / 2;
    dim3 gridB((ngroups + 255) / 256, BATCH);
    kge_gather_kernel<<<gridB, 256, 0, stream>>>(neg, dist, out, nneg);
}

// Round 5
// 166.248 us; speedup vs baseline: 1.4175x; 1.0816x over previous
//
#include <hip/hip_runtime.h>

#define HIDDEN 256
#define GAMMA_F 12.0f
#define BATCH 8

// ---------------------------------------------------------------------------
// Kernel A: stream the entity table once. Lane i covers dims [4i, 4i+4), so
// each float4 load inst moves one FULL 1KB row of unique contiguous data
// (r4's 8-way-replicated layout delivered only 128B/inst -> 1.7 TB/s cap).
// 8 rows per iteration: 8KB of loads issued before any use (real MLP).
// Per row: 8 batch partials/lane (fabs folds into VOP3 input modifier ->
// 2 VALU/elem), then a 10-shuffle merge-tree: offsets 1,2,4 fold the batch
// index into lane bits 0..2, offsets 8,16,32 butterfly -> lane l holds the
// complete sum for batch l&7. Row r latches into lanes [8r, 8r+8), so each
// 8-row group ends with ONE dense 256B store: dist[grp*64 + lane].
// ---------------------------------------------------------------------------
__global__ __launch_bounds__(256) void kge_dist_kernel(
    const float* __restrict__ ent,
    const float* __restrict__ rel,
    const int*  __restrict__ pos,
    float* __restrict__ dist,   // [nent, 8]
    int ngroups, int nent)
{
    const int lane = threadIdx.x & 63;
    const int wave_gid = (blockIdx.x * 256 + threadIdx.x) >> 6;
    const int nwaves = gridDim.x * 4;

    // hr[b] = head_b + rel_b at dims [4*lane, 4*lane+4) — 32 VGPRs, once
    float4 hr[BATCH];
    #pragma unroll
    for (int b = 0; b < BATCH; ++b) {
        const int hidx = pos[b * 3 + 0];
        const int ridx = pos[b * 3 + 1];
        const float4 h4 = *(const float4*)(ent + (size_t)hidx * HIDDEN + lane * 4);
        const float4 r4 = *(const float4*)(rel + (size_t)ridx * HIDDEN + lane * 4);
        hr[b] = make_float4(h4.x + r4.x, h4.y + r4.y, h4.z + r4.z, h4.w + r4.w);
    }

    for (int grp = wave_gid; grp < ngroups; grp += nwaves) {
        const float* base = ent + (size_t)grp * 8 * HIDDEN + lane * 4;

        // 8 full-row loads (8KB unique, contiguous) issued before any use
        float4 t[8];
        #pragma unroll
        for (int r = 0; r < 8; ++r)
            t[r] = *(const float4*)(base + r * HIDDEN);

        float res = 0.0f;
        #pragma unroll
        for (int r = 0; r < 8; ++r) {
            float acc[BATCH];
            #pragma unroll
            for (int b = 0; b < BATCH; ++b) {
                acc[b] = fabsf(hr[b].x - t[r].x) + fabsf(hr[b].y - t[r].y)
                       + fabsf(hr[b].z - t[r].z) + fabsf(hr[b].w - t[r].w);
            }
            // fold batch bits into lane bits 0..2
            float v[4];
            {
                const bool p = lane & 1;
                #pragma unroll
                for (int k = 0; k < 4; ++k) {
                    const float keep = p ? acc[2 * k + 1] : acc[2 * k];
                    const float give = p ? acc[2 * k]     : acc[2 * k + 1];
                    v[k] = keep + __shfl_xor(give, 1, 64);
                }
            }
            float w2[2];
            {
                const bool p = (lane >> 1) & 1;
                #pragma unroll
                for (int k = 0; k < 2; ++k) {
                    const float keep = p ? v[2 * k + 1] : v[2 * k];
                    const float give = p ? v[2 * k]     : v[2 * k + 1];
                    w2[k] = keep + __shfl_xor(give, 2, 64);
                }
            }
            float s;
            {
                const bool p = (lane >> 2) & 1;
                const float keep = p ? w2[1] : w2[0];
                const float give = p ? w2[0] : w2[1];
                s = keep + __shfl_xor(give, 4, 64);
            }
            // butterfly across the 8 dim-groups: every lane gets batch lane&7
            s += __shfl_xor(s, 8, 64);
            s += __shfl_xor(s, 16, 64);
            s += __shfl_xor(s, 32, 64);
            if ((lane >> 3) == r) res = GAMMA_F - s;
        }
        // dense 256B store: lane r*8+b -> dist[(grp*8+r)*8 + b]
        dist[(size_t)grp * 64 + lane] = res;
    }

    // tail rows (none at nent=100000): wave 0 handles them one at a time
    if (wave_gid == 0) {
        for (int e = ngroups * 8; e < nent; ++e) {
            const float4 t4 = *(const float4*)(ent + (size_t)e * HIDDEN + lane * 4);
            float acc[BATCH];
            #pragma unroll
            for (int b = 0; b < BATCH; ++b) {
                acc[b] = fabsf(hr[b].x - t4.x) + fabsf(hr[b].y - t4.y)
                       + fabsf(hr[b].z - t4.z) + fabsf(hr[b].w - t4.w);
            }
            float v[4];
            {
                const bool p = lane & 1;
                #pragma unroll
                for (int k = 0; k < 4; ++k) {
                    const float keep = p ? acc[2 * k + 1] : acc[2 * k];
                    const float give = p ? acc[2 * k]     : acc[2 * k + 1];
                    v[k] = keep + __shfl_xor(give, 1, 64);
                }
            }
            float w2[2];
            {
                const bool p = (lane >> 1) & 1;
                #pragma unroll
                for (int k = 0; k < 2; ++k) {
                    const float keep = p ? v[2 * k + 1] : v[2 * k];
                    const float give = p ? v[2 * k]     : v[2 * k + 1];
                    w2[k] = keep + __shfl_xor(give, 2, 64);
                }
            }
            float s;
            {
                const bool p = (lane >> 2) & 1;
                const float keep = p ? w2[1] : w2[0];
                const float give = p ? w2[0] : w2[1];
                s = keep + __shfl_xor(give, 4, 64);
            }
            s += __shfl_xor(s, 8, 64);
            s += __shfl_xor(s, 16, 64);
            s += __shfl_xor(s, 32, 64);
            if (lane < BATCH) dist[(size_t)e * BATCH + lane] = GAMMA_F - s;
        }
    }
}

// ---------------------------------------------------------------------------
// Kernel B: out[b,n] = dist[neg[b,n]*8 + b]. dist (3.2MB) is L2-resident.
// 2 outputs/thread: int2 index load, 2 independent gathers, float2 store.
// ---------------------------------------------------------------------------
__global__ __launch_bounds__(256) void kge_gather_kernel(
    const int*  __restrict__ neg,
    const float* __restrict__ dist,
    float* __restrict__ out,
    int nneg)
{
    const int b = blockIdx.y;
    const int n = (blockIdx.x * 256 + threadIdx.x) * 2;
    if (n + 1 < nneg) {
        const int2 idx = *(const int2*)(neg + (size_t)b * nneg + n);
        float2 r;
        r.x = dist[(size_t)idx.x * BATCH + b];
        r.y = dist[(size_t)idx.y * BATCH + b];
        *(float2*)(out + (size_t)b * nneg + n) = r;
    } else if (n < nneg) {
        out[(size_t)b * nneg + n] =
            dist[(size_t)neg[(size_t)b * nneg + n] * BATCH + b];
    }
}

extern "C" void kernel_launch(void* const* d_in, const int* in_sizes, int n_in,
                              void* d_out, int out_size, void* d_ws, size_t ws_size,
                              hipStream_t stream) {
    const float* ent = (const float*)d_in[0];   // [100000, 256] f32
    const float* rel = (const float*)d_in[1];   // [500, 256]    f32
    const int*   pos = (const int*)d_in[2];     // [8, 3]        int32
    const int*   neg = (const int*)d_in[3];     // [8, 100000]   int32
    float* out = (float*)d_out;                 // [8, 100000]   f32

    const int nent = in_sizes[0] / HIDDEN;      // 100000
    const int nneg = in_sizes[3] / BATCH;       // 100000
    float* dist = (float*)d_ws;                 // 3.2 MB (ws is larger)

    const int ngroups = nent / 8;               // 12500 full 8-row groups
    // 1024 blocks = 4096 waves (4/SIMD resident at VGPR<=128), ~3 groups/wave
    kge_dist_kernel<<<1024, 256, 0, stream>>>(ent, rel, pos, dist, ngroups, nent);

    const int npairs = (nneg + 1) / 2;
    dim3 gridB((npairs + 255) / 256, BATCH);
    kge_gather_kernel<<<gridB, 256, 0, stream>>>(neg, dist, out, nneg);
}

// Round 6
// 165.997 us; speedup vs baseline: 1.4196x; 1.0015x over previous
//
#include <hip/hip_runtime.h>

#define HIDDEN 256
#define GAMMA_F 12.0f
#define BATCH 8

// ---------------------------------------------------------------------------
// Kernel A: stream the entity table once (persistent waves, 8 rows/iter).
// Lane layout: r = lane>>5 (row within pair), c = lane&31 (dim chunk).
// Lane covers 8 dims of row r: [4c,4c+4) and [128+4c,128+4c+4), so each
// float4 load inst moves 1KB unique contiguous (two adjacent rows' halves).
// Reduction: ONE 5-level merge tree per ROW-PAIR (not per row): levels
// xor 1,2,4 fold the 3 batch bits into lane bits 0..2 (select+add), levels
// xor 8,16 are plain butterflies. 9 shuffles / 2 rows (was 10 / row), and
// the 4 pair-trees per group are independent -> shuffle latency overlaps.
// After the tree, lane l holds sum for (rowpair r=l>>5, batch b=l&7),
// replicated over lane bits 3,4 — set j latches into lanes (l>>3)&3 == j,
// giving one dense 256B store per 8-row group.
// ---------------------------------------------------------------------------
__global__ __launch_bounds__(256) void kge_dist_kernel(
    const float* __restrict__ ent,
    const float* __restrict__ rel,
    const int*  __restrict__ pos,
    float* __restrict__ dist,   // [nent, 8]
    int ngroups, int nent)
{
    const int lane = threadIdx.x & 63;
    const int r = lane >> 5;
    const int c = lane & 31;
    const int wave_gid = (blockIdx.x * 256 + threadIdx.x) >> 6;
    const int nwaves = gridDim.x * 4;

    // hr[b] = head_b + rel_b at this lane's 8 dims (64 VGPRs, loaded once)
    float4 hrA[BATCH], hrB[BATCH];
    #pragma unroll
    for (int b = 0; b < BATCH; ++b) {
        const int hidx = pos[b * 3 + 0];
        const int ridx = pos[b * 3 + 1];
        const float* hrow = ent + (size_t)hidx * HIDDEN;
        const float* rrow = rel + (size_t)ridx * HIDDEN;
        float4 h = *(const float4*)(hrow + c * 4);
        float4 q = *(const float4*)(rrow + c * 4);
        hrA[b] = make_float4(h.x + q.x, h.y + q.y, h.z + q.z, h.w + q.w);
        h = *(const float4*)(hrow + 128 + c * 4);
        q = *(const float4*)(rrow + 128 + c * 4);
        hrB[b] = make_float4(h.x + q.x, h.y + q.y, h.z + q.z, h.w + q.w);
    }

    for (int grp = wave_gid; grp < ngroups; grp += nwaves) {
        const float* base = ent + (size_t)grp * 8 * HIDDEN;

        // 8 loads (8KB unique contiguous) issued before any use
        float4 tA[4], tB[4];
        #pragma unroll
        for (int j = 0; j < 4; ++j) {
            const float* rowb = base + (size_t)(2 * j + r) * HIDDEN;
            tA[j] = *(const float4*)(rowb + c * 4);
            tB[j] = *(const float4*)(rowb + 128 + c * 4);
        }

        float res = 0.0f;
        #pragma unroll
        for (int j = 0; j < 4; ++j) {
            float acc[BATCH];
            #pragma unroll
            for (int b = 0; b < BATCH; ++b) {
                acc[b] = fabsf(hrA[b].x - tA[j].x) + fabsf(hrA[b].y - tA[j].y)
                       + fabsf(hrA[b].z - tA[j].z) + fabsf(hrA[b].w - tA[j].w)
                       + fabsf(hrB[b].x - tB[j].x) + fabsf(hrB[b].y - tB[j].y)
                       + fabsf(hrB[b].z - tB[j].z) + fabsf(hrB[b].w - tB[j].w);
            }
            // fold batch bits into lane bits 0..2
            float v[4];
            {
                const bool p = lane & 1;
                #pragma unroll
                for (int k = 0; k < 4; ++k) {
                    const float keep = p ? acc[2 * k + 1] : acc[2 * k];
                    const float give = p ? acc[2 * k]     : acc[2 * k + 1];
                    v[k] = keep + __shfl_xor(give, 1, 64);
                }
            }
            float w2[2];
            {
                const bool p = (lane >> 1) & 1;
                #pragma unroll
                for (int k = 0; k < 2; ++k) {
                    const float keep = p ? v[2 * k + 1] : v[2 * k];
                    const float give = p ? v[2 * k]     : v[2 * k + 1];
                    w2[k] = keep + __shfl_xor(give, 2, 64);
                }
            }
            float s;
            {
                const bool p = (lane >> 2) & 1;
                const float keep = p ? w2[1] : w2[0];
                const float give = p ? w2[0] : w2[1];
                s = keep + __shfl_xor(give, 4, 64);
            }
            // butterflies over remaining dim-chunk bits (3,4)
            s += __shfl_xor(s, 8, 64);
            s += __shfl_xor(s, 16, 64);
            // replicated over bits 3,4 — latch copy j
            if (((lane >> 3) & 3) == j) res = GAMMA_F - s;
        }
        // lane l -> e_local = 2*((l>>3)&3) + (l>>5), batch = l&7 (bijection)
        dist[(size_t)grp * 64 + ((lane >> 3) & 3) * 16 + r * 8 + (lane & 7)] = res;
    }

    // tail rows (none at nent=100000): 32 lanes cover the row, r duplicates
    if (wave_gid == 0) {
        for (int e = ngroups * 8; e < nent; ++e) {
            const float* rowb = ent + (size_t)e * HIDDEN;
            const float4 uA = *(const float4*)(rowb + c * 4);
            const float4 uB = *(const float4*)(rowb + 128 + c * 4);
            float acc[BATCH];
            #pragma unroll
            for (int b = 0; b < BATCH; ++b) {
                acc[b] = fabsf(hrA[b].x - uA.x) + fabsf(hrA[b].y - uA.y)
                       + fabsf(hrA[b].z - uA.z) + fabsf(hrA[b].w - uA.w)
                       + fabsf(hrB[b].x - uB.x) + fabsf(hrB[b].y - uB.y)
                       + fabsf(hrB[b].z - uB.z) + fabsf(hrB[b].w - uB.w);
            }
            float v[4];
            {
                const bool p = lane & 1;
                #pragma unroll
                for (int k = 0; k < 4; ++k) {
                    const float keep = p ? acc[2 * k + 1] : acc[2 * k];
                    const float give = p ? acc[2 * k]     : acc[2 * k + 1];
                    v[k] = keep + __shfl_xor(give, 1, 64);
                }
            }
            float w2[2];
            {
                const bool p = (lane >> 1) & 1;
                #pragma unroll
                for (int k = 0; k < 2; ++k) {
                    const float keep = p ? v[2 * k + 1] : v[2 * k];
                    const float give = p ? v[2 * k]     : v[2 * k + 1];
                    w2[k] = keep + __shfl_xor(give, 2, 64);
                }
            }
            float s;
            {
                const bool p = (lane >> 2) & 1;
                const float keep = p ? w2[1] : w2[0];
                const float give = p ? w2[0] : w2[1];
                s = keep + __shfl_xor(give, 4, 64);
            }
            s += __shfl_xor(s, 8, 64);
            s += __shfl_xor(s, 16, 64);
            // lanes 0..7 (r==0 half) hold complete sums for batches 0..7
            if (lane < BATCH) dist[(size_t)e * BATCH + lane] = GAMMA_F - s;
        }
    }
}

// ---------------------------------------------------------------------------
// Kernel B: out[b,n] = dist[neg[b,n]*8 + b]. dist (3.2MB) is L2-resident.
// ---------------------------------------------------------------------------
__global__ __launch_bounds__(256) void kge_gather_kernel(
    const int*  __restrict__ neg,
    const float* __restrict__ dist,
    float* __restrict__ out,
    int nneg)
{
    const int b = blockIdx.y;
    const int n = (blockIdx.x * 256 + threadIdx.x) * 2;
    if (n + 1 < nneg) {
        const int2 idx = *(const int2*)(neg + (size_t)b * nneg + n);
        float2 r;
        r.x = dist[(size_t)idx.x * BATCH + b];
        r.y = dist[(size_t)idx.y * BATCH + b];
        *(float2*)(out + (size_t)b * nneg + n) = r;
    } else if (n < nneg) {
        out[(size_t)b * nneg + n] =
            dist[(size_t)neg[(size_t)b * nneg + n] * BATCH + b];
    }
}

extern "C" void kernel_launch(void* const* d_in, const int* in_sizes, int n_in,
                              void* d_out, int out_size, void* d_ws, size_t ws_size,
                              hipStream_t stream) {
    const float* ent = (const float*)d_in[0];   // [100000, 256] f32
    const float* rel = (const float*)d_in[1];   // [500, 256]    f32
    const int*   pos = (const int*)d_in[2];     // [8, 3]        int32
    const int*   neg = (const int*)d_in[3];     // [8, 100000]   int32
    float* out = (float*)d_out;                 // [8, 100000]   f32

    const int nent = in_sizes[0] / HIDDEN;      // 100000
    const int nneg = in_sizes[3] / BATCH;       // 100000
    float* dist = (float*)d_ws;                 // 3.2 MB (ws is larger)

    const int ngroups = nent / 8;               // 12500 full 8-row groups
    kge_dist_kernel<<<1024, 256, 0, stream>>>(ent, rel, pos, dist, ngroups, nent);

    const int npairs = (nneg + 1) / 2;
    dim3 gridB((npairs + 255) / 256, BATCH);
    kge_gather_kernel<<<gridB, 256, 0, stream>>>(neg, dist, out, nneg);
}